// Round 5
// baseline (46.053 us; speedup 1.0000x reference)
//
#include <hip/hip_runtime.h>
#include <hip/hip_bf16.h>

#define BATCH 16
#define FRAMES 8192
#define TLEN 512
#define EDIM 256
#define SP 56  // LDS row stride in shorts (112B): 16B-aligned, 2-way bank aliasing max

typedef __attribute__((ext_vector_type(8))) short short8;
typedef __attribute__((ext_vector_type(4))) float f32x4;

__device__ __forceinline__ unsigned cvt2(float lo, float hi) {
    __hip_bfloat162 t = __float22bfloat162_rn(make_float2(lo, hi));  // v_cvt_pk_bf16_f32
    return *reinterpret_cast<unsigned*>(&t);
}
__device__ __forceinline__ unsigned long long pack4(f32x4 u) {
    return (unsigned long long)cvt2(u[0], u[1]) |
           ((unsigned long long)cvt2(u[2], u[3]) << 32);
}

// ---------------------------------------------------------------------------
// k_prep (256 blocks, 512 thr):
//   blocks 0..127   G[row][d] = sum_e enc[row][e]*(W+I)[d][e]  (= enc + enc·Wt)
//   blocks 128..255 Q[f][d]   = sum_e PE[f][e]*W[d][e] + pos_b[d]+pit_b[d]
//   blocks 240..255 ALSO run the aligner scan for batch (bid-240) BEFORE GEMM
// GEMM: round-2-proven structure — 64 rows/block, 8 waves (4 row-groups x
// 2 col-halves), 8 K-steps of 32, single-buffered LDS, cvt_pk bf16 staging.
// ---------------------------------------------------------------------------
__global__ __launch_bounds__(512) void k_prep(const float* __restrict__ X,
                                              const float* __restrict__ W,
                                              const float* __restrict__ pos_b,
                                              const float* __restrict__ pit_b,
                                              const int* __restrict__ ap,
                                              const int* __restrict__ tp,
                                              float* __restrict__ G,
                                              float* __restrict__ Q,
                                              int* __restrict__ inds) {
    __shared__ short lds[(64 + 256) * SP];  // 35840 B
    int bid = blockIdx.x;
    int tid = threadIdx.x;

    if (bid >= 240) {
        // ---------------- aligner scan (then fall through to GEMM) ----------
        int b = bid - 240;
        int* tps = (int*)lds;          // 512 ints
        int* wsum = tps + TLEN;        // 8 ints
        int* okp = wsum + 8;
        const int* apb = ap + b * FRAMES;
        tps[tid] = tp[b * TLEN + tid];
        if (tid == 0) *okp = 1;
        __syncthreads();
        int j0 = tid * 16;
        int4 v0 = ((const int4*)apb)[tid * 4];
        int4 v1 = ((const int4*)apb)[tid * 4 + 1];
        int4 v2 = ((const int4*)apb)[tid * 4 + 2];
        int4 v3 = ((const int4*)apb)[tid * 4 + 3];
        int a[16] = {v0.x, v0.y, v0.z, v0.w, v1.x, v1.y, v1.z, v1.w,
                     v2.x, v2.y, v2.z, v2.w, v3.x, v3.y, v3.z, v3.w};
        int pr = (tid == 0) ? a[0] : apb[j0 - 1];
        int c = 0, p[16];
#pragma unroll
        for (int k = 0; k < 16; ++k) {
            c += ((j0 + k) > 0) && (a[k] != pr);
            p[k] = c;
            pr = a[k];
        }
        int lane = tid & 63, wv = tid >> 6;
        int sc = c;
#pragma unroll
        for (int d = 1; d < 64; d <<= 1) {
            int o = __shfl_up(sc, d);
            if (lane >= d) sc += o;
        }
        if (lane == 63) wsum[wv] = sc;
        __syncthreads();
        int wbase = 0;
        for (int w = 0; w < wv; ++w) wbase += wsum[w];
        int excl = wbase + sc - c;
        int g[16];
#pragma unroll
        for (int k = 0; k < 16; ++k) g[k] = min(excl + p[k], TLEN - 1);
        int4* ob = (int4*)(inds + b * FRAMES);
#pragma unroll
        for (int q4 = 0; q4 < 4; ++q4) {
            int4 wv4;
            wv4.x = g[q4 * 4]; wv4.y = g[q4 * 4 + 1];
            wv4.z = g[q4 * 4 + 2]; wv4.w = g[q4 * 4 + 3];
            ob[tid * 4 + q4] = wv4;
        }
        int ok = 1, gp = min(excl, TLEN - 1);
#pragma unroll
        for (int k = 0; k < 16; ++k) {
            int j = j0 + k, e;
            if (j == 0) e = 0;
            else e = (a[k] == tps[gp]) ? gp : min(gp + 1, TLEN - 1);
            ok &= (g[k] == e);
            gp = g[k];
        }
        if (!ok) atomicAnd(okp, 0);
        __syncthreads();
        if (*okp == 0 && tid == 0) {  // exact serial fallback (never for this input)
            int ind = 0, cur = tps[0];
            int* o = inds + b * FRAMES;
            o[0] = 0;
            for (int j = 1; j < FRAMES; ++j) {
                int aj = apb[j];
                if (aj != cur && ind < TLEN - 1) { ind++; cur = tps[ind]; }
                o[j] = ind;
            }
        }
        // fall through to GEMM (first loop iteration starts with __syncthreads)
    }

    // ---------------- GEMM path ----------------
    int qmode = (bid >= 128);
    int row0 = (qmode ? bid - 128 : bid) * 64;
    short* Xs = lds;            // 64 x SP
    short* Ws = lds + 64 * SP;  // 256 x SP
    int lane = tid & 63, wv = tid >> 6;
    int c = lane & 15, gq = lane >> 4;
    int r0 = (wv & 3) * 16, cc0 = (wv >> 2) * 128;
    int sr = tid >> 3, spart = tid & 7;  // staging decomposition
    f32x4 acc[8];
#pragma unroll
    for (int i = 0; i < 8; ++i) acc[i] = (f32x4){0.f, 0.f, 0.f, 0.f};

    const float kPE = -0.03597789207803197f;     // -ln(10000)/256
    const float INV2PI = 0.15915494309189535f;

    for (int ks = 0; ks < 8; ++ks) {
        int k0 = ks * 32;
        __syncthreads();
        {   // stage X tile [64 r][32 k] (4 elems/thread)
            unsigned long long pk;
            if (!qmode) {
                f32x4 u = *(const f32x4*)(X + (row0 + sr) * EDIM + k0 + spart * 4);
                pk = pack4(u);
            } else {
                float fr = (float)(row0 + sr);
                int e0 = k0 + spart * 4;
                float dv0 = __expf((float)e0 * kPE);
                float dv1 = __expf((float)(e0 + 2) * kPE);
                float a0 = fr * dv0 * INV2PI; a0 -= floorf(a0);
                float a1 = fr * dv1 * INV2PI; a1 -= floorf(a1);
                f32x4 v;
                v[0] = __builtin_amdgcn_sinf(a0);
                v[1] = __builtin_amdgcn_cosf(a0);
                v[2] = __builtin_amdgcn_sinf(a1);
                v[3] = __builtin_amdgcn_cosf(a1);
                pk = pack4(v);
            }
            *((unsigned long long*)&Xs[sr * SP + spart * 4]) = pk;
        }
#pragma unroll
        for (int m = 0; m < 4; ++m) {  // stage W tile [256 d][32 k], +I for G-path
            int d = sr + 64 * m;
            f32x4 u = *(const f32x4*)(W + d * EDIM + k0 + spart * 4);
            if (!qmode) {
#pragma unroll
                for (int j = 0; j < 4; ++j)
                    if (d == k0 + spart * 4 + j) u[j] += 1.0f;
            }
            *((unsigned long long*)&Ws[d * SP + spart * 4]) = pack4(u);
        }
        __syncthreads();
        short8 af = *((const short8*)&Xs[(r0 + c) * SP + gq * 8]);
#pragma unroll
        for (int tc = 0; tc < 8; ++tc) {
            short8 bf = *((const short8*)&Ws[(cc0 + tc * 16 + c) * SP + gq * 8]);
            acc[tc] = __builtin_amdgcn_mfma_f32_16x16x32_bf16(af, bf, acc[tc], 0, 0, 0);
        }
    }
    // epilogue: C/D layout col=lane&15, row=(lane>>4)*4+i
    int mrow = row0 + r0 + gq * 4;
    if (!qmode) {
#pragma unroll
        for (int tc = 0; tc < 8; ++tc) {
            int d = cc0 + tc * 16 + c;
#pragma unroll
            for (int i = 0; i < 4; ++i)
                G[(mrow + i) * EDIM + d] = acc[tc][i];
        }
    } else {
#pragma unroll
        for (int tc = 0; tc < 8; ++tc) {
            int d = cc0 + tc * 16 + c;
            float bb = pos_b[d] + pit_b[d];
#pragma unroll
            for (int i = 0; i < 4; ++i)
                Q[(mrow + i) * EDIM + d] = acc[tc][i] + bb;
        }
    }
}

// ---------------------------------------------------------------------------
// k_final: 1024 blocks; block owns 8 frames x 16 batches; wave owns 4 batches.
// Unconditional G load (G/Q are LLC-resident). XCD-chunked bijective swizzle.
// out[b,f,:] = G[b,ind,:] + Q[f,:] + pitch*wp + EB[beat]
// ---------------------------------------------------------------------------
__global__ __launch_bounds__(256) void k_final(const float* __restrict__ G,
                                               const float* __restrict__ Q,
                                               const int* __restrict__ inds,
                                               const float* __restrict__ pitch,
                                               const int* __restrict__ beats,
                                               const float* __restrict__ wp,
                                               const float* __restrict__ eb,
                                               float* __restrict__ out) {
    // bijective XCD swizzle: 1024 blocks, 8 XCDs, 128 chunks each
    int swz = (blockIdx.x & 7) * 128 + (blockIdx.x >> 3);
    int f0 = swz * 8;
    int wv = threadIdx.x >> 6, lane = threadIdx.x & 63;
    f32x4 w4 = ((const f32x4*)wp)[lane];
    f32x4 e0 = ((const f32x4*)eb)[lane];
    f32x4 e1 = ((const f32x4*)eb)[64 + lane];
#pragma unroll
    for (int f = 0; f < 8; ++f) {
        f32x4 q = ((const f32x4*)Q)[(f0 + f) * 64 + lane];
#pragma unroll
        for (int bb = 0; bb < 4; ++bb) {
            int b = wv * 4 + bb;
            int idx = b * FRAMES + f0 + f;
            int ind = inds[idx];
            float p = pitch[idx];
            int bt = beats[idx];
            f32x4 g = ((const f32x4*)G)[(b * TLEN + ind) * 64 + lane];
            f32x4 e = bt ? e1 : e0;
            f32x4 r;
#pragma unroll
            for (int i = 0; i < 4; ++i) r[i] = g[i] + q[i] + p * w4[i] + e[i];
            __builtin_nontemporal_store(r, &((f32x4*)out)[idx * 64 + lane]);
        }
    }
}

extern "C" void kernel_launch(void* const* d_in, const int* in_sizes, int n_in,
                              void* d_out, int out_size, void* d_ws, size_t ws_size,
                              hipStream_t stream) {
    const float* enc   = (const float*)d_in[0];  // [16,512,256]
    const int*   ap    = (const int*)d_in[1];    // [16,8192]
    const int*   tp    = (const int*)d_in[2];    // [16,512]
    const float* pitch = (const float*)d_in[3];  // [16,8192,1]
    const int*   beats = (const int*)d_in[4];    // [16,8192,1]
    const float* wpit  = (const float*)d_in[5];  // [256,1]
    const float* bpit  = (const float*)d_in[6];  // [256]
    const float* wpos  = (const float*)d_in[7];  // [256,256]
    const float* bpos  = (const float*)d_in[8];  // [256]
    const float* ebts  = (const float*)d_in[9];  // [2,256]
    float* out = (float*)d_out;
    char* ws = (char*)d_ws;
    int*   inds = (int*)ws;                   // 512 KB
    float* G    = (float*)(ws + (1 << 20));   // 8 MB
    float* Q    = (float*)(ws + (9 << 20));   // 8 MB

    hipLaunchKernelGGL(k_prep, dim3(256), dim3(512), 0, stream,
                       enc, wpos, bpos, bpit, ap, tp, G, Q, inds);
    hipLaunchKernelGGL(k_final, dim3(1024), dim3(256), 0, stream,
                       G, Q, inds, pitch, beats, wpit, ebts, out);
}

// Round 6
// 44.556 us; speedup vs baseline: 1.0336x; 1.0336x over previous
//
#include <hip/hip_runtime.h>
#include <hip/hip_bf16.h>

#define BATCH 16
#define FRAMES 8192
#define TLEN 512
#define EDIM 256
#define SP 56  // LDS row stride in shorts (112B): 16B-aligned, 2-way bank aliasing max

typedef __attribute__((ext_vector_type(8))) short short8;
typedef __attribute__((ext_vector_type(4))) float f32x4;

__device__ __forceinline__ unsigned cvt2(float lo, float hi) {
    __hip_bfloat162 t = __float22bfloat162_rn(make_float2(lo, hi));  // v_cvt_pk_bf16_f32
    return *reinterpret_cast<unsigned*>(&t);
}
__device__ __forceinline__ unsigned long long pack4(f32x4 u) {
    return (unsigned long long)cvt2(u[0], u[1]) |
           ((unsigned long long)cvt2(u[2], u[3]) << 32);
}

// ---------------------------------------------------------------------------
// k_prep (256 blocks, 512 thr)  [round-5 proven, unchanged]:
//   blocks 0..127   G[row][d] = sum_e enc[row][e]*(W+I)[d][e]  (= enc + enc·Wt)
//   blocks 128..255 Q[f][d]   = sum_e PE[f][e]*W[d][e] + pos_b[d]+pit_b[d]
//   blocks 240..255 ALSO run the aligner scan for batch (bid-240) BEFORE GEMM
// ---------------------------------------------------------------------------
__global__ __launch_bounds__(512) void k_prep(const float* __restrict__ X,
                                              const float* __restrict__ W,
                                              const float* __restrict__ pos_b,
                                              const float* __restrict__ pit_b,
                                              const int* __restrict__ ap,
                                              const int* __restrict__ tp,
                                              float* __restrict__ G,
                                              float* __restrict__ Q,
                                              int* __restrict__ inds) {
    __shared__ short lds[(64 + 256) * SP];  // 35840 B
    int bid = blockIdx.x;
    int tid = threadIdx.x;

    if (bid >= 240) {
        // ---------------- aligner scan (then fall through to GEMM) ----------
        int b = bid - 240;
        int* tps = (int*)lds;          // 512 ints
        int* wsum = tps + TLEN;        // 8 ints
        int* okp = wsum + 8;
        const int* apb = ap + b * FRAMES;
        tps[tid] = tp[b * TLEN + tid];
        if (tid == 0) *okp = 1;
        __syncthreads();
        int j0 = tid * 16;
        int4 v0 = ((const int4*)apb)[tid * 4];
        int4 v1 = ((const int4*)apb)[tid * 4 + 1];
        int4 v2 = ((const int4*)apb)[tid * 4 + 2];
        int4 v3 = ((const int4*)apb)[tid * 4 + 3];
        int a[16] = {v0.x, v0.y, v0.z, v0.w, v1.x, v1.y, v1.z, v1.w,
                     v2.x, v2.y, v2.z, v2.w, v3.x, v3.y, v3.z, v3.w};
        int pr = (tid == 0) ? a[0] : apb[j0 - 1];
        int c = 0, p[16];
#pragma unroll
        for (int k = 0; k < 16; ++k) {
            c += ((j0 + k) > 0) && (a[k] != pr);
            p[k] = c;
            pr = a[k];
        }
        int lane = tid & 63, wv = tid >> 6;
        int sc = c;
#pragma unroll
        for (int d = 1; d < 64; d <<= 1) {
            int o = __shfl_up(sc, d);
            if (lane >= d) sc += o;
        }
        if (lane == 63) wsum[wv] = sc;
        __syncthreads();
        int wbase = 0;
        for (int w = 0; w < wv; ++w) wbase += wsum[w];
        int excl = wbase + sc - c;
        int g[16];
#pragma unroll
        for (int k = 0; k < 16; ++k) g[k] = min(excl + p[k], TLEN - 1);
        int4* ob = (int4*)(inds + b * FRAMES);
#pragma unroll
        for (int q4 = 0; q4 < 4; ++q4) {
            int4 wv4;
            wv4.x = g[q4 * 4]; wv4.y = g[q4 * 4 + 1];
            wv4.z = g[q4 * 4 + 2]; wv4.w = g[q4 * 4 + 3];
            ob[tid * 4 + q4] = wv4;
        }
        int ok = 1, gp = min(excl, TLEN - 1);
#pragma unroll
        for (int k = 0; k < 16; ++k) {
            int j = j0 + k, e;
            if (j == 0) e = 0;
            else e = (a[k] == tps[gp]) ? gp : min(gp + 1, TLEN - 1);
            ok &= (g[k] == e);
            gp = g[k];
        }
        if (!ok) atomicAnd(okp, 0);
        __syncthreads();
        if (*okp == 0 && tid == 0) {  // exact serial fallback (never for this input)
            int ind = 0, cur = tps[0];
            int* o = inds + b * FRAMES;
            o[0] = 0;
            for (int j = 1; j < FRAMES; ++j) {
                int aj = apb[j];
                if (aj != cur && ind < TLEN - 1) { ind++; cur = tps[ind]; }
                o[j] = ind;
            }
        }
        // fall through to GEMM (first loop iteration starts with __syncthreads)
    }

    // ---------------- GEMM path ----------------
    int qmode = (bid >= 128);
    int row0 = (qmode ? bid - 128 : bid) * 64;
    short* Xs = lds;            // 64 x SP
    short* Ws = lds + 64 * SP;  // 256 x SP
    int lane = tid & 63, wv = tid >> 6;
    int c = lane & 15, gq = lane >> 4;
    int r0 = (wv & 3) * 16, cc0 = (wv >> 2) * 128;
    int sr = tid >> 3, spart = tid & 7;  // staging decomposition
    f32x4 acc[8];
#pragma unroll
    for (int i = 0; i < 8; ++i) acc[i] = (f32x4){0.f, 0.f, 0.f, 0.f};

    const float kPE = -0.03597789207803197f;     // -ln(10000)/256
    const float INV2PI = 0.15915494309189535f;

    for (int ks = 0; ks < 8; ++ks) {
        int k0 = ks * 32;
        __syncthreads();
        {   // stage X tile [64 r][32 k] (4 elems/thread)
            unsigned long long pk;
            if (!qmode) {
                f32x4 u = *(const f32x4*)(X + (row0 + sr) * EDIM + k0 + spart * 4);
                pk = pack4(u);
            } else {
                float fr = (float)(row0 + sr);
                int e0 = k0 + spart * 4;
                float dv0 = __expf((float)e0 * kPE);
                float dv1 = __expf((float)(e0 + 2) * kPE);
                float a0 = fr * dv0 * INV2PI; a0 -= floorf(a0);
                float a1 = fr * dv1 * INV2PI; a1 -= floorf(a1);
                f32x4 v;
                v[0] = __builtin_amdgcn_sinf(a0);
                v[1] = __builtin_amdgcn_cosf(a0);
                v[2] = __builtin_amdgcn_sinf(a1);
                v[3] = __builtin_amdgcn_cosf(a1);
                pk = pack4(v);
            }
            *((unsigned long long*)&Xs[sr * SP + spart * 4]) = pk;
        }
#pragma unroll
        for (int m = 0; m < 4; ++m) {  // stage W tile [256 d][32 k], +I for G-path
            int d = sr + 64 * m;
            f32x4 u = *(const f32x4*)(W + d * EDIM + k0 + spart * 4);
            if (!qmode) {
#pragma unroll
                for (int j = 0; j < 4; ++j)
                    if (d == k0 + spart * 4 + j) u[j] += 1.0f;
            }
            *((unsigned long long*)&Ws[d * SP + spart * 4]) = pack4(u);
        }
        __syncthreads();
        short8 af = *((const short8*)&Xs[(r0 + c) * SP + gq * 8]);
#pragma unroll
        for (int tc = 0; tc < 8; ++tc) {
            short8 bf = *((const short8*)&Ws[(cc0 + tc * 16 + c) * SP + gq * 8]);
            acc[tc] = __builtin_amdgcn_mfma_f32_16x16x32_bf16(af, bf, acc[tc], 0, 0, 0);
        }
    }
    // epilogue: C/D layout col=lane&15, row=(lane>>4)*4+i
    int mrow = row0 + r0 + gq * 4;
    if (!qmode) {
#pragma unroll
        for (int tc = 0; tc < 8; ++tc) {
            int d = cc0 + tc * 16 + c;
#pragma unroll
            for (int i = 0; i < 4; ++i)
                G[(mrow + i) * EDIM + d] = acc[tc][i];
        }
    } else {
#pragma unroll
        for (int tc = 0; tc < 8; ++tc) {
            int d = cc0 + tc * 16 + c;
            float bb = pos_b[d] + pit_b[d];
#pragma unroll
            for (int i = 0; i < 4; ++i)
                Q[(mrow + i) * EDIM + d] = acc[tc][i] + bb;
        }
    }
}

// ---------------------------------------------------------------------------
// k_final v3: 1024 blocks; block owns 8 frames x 16 batches; wave owns 4
// batches. Q rows hoisted to registers; metadata (inds/pitch/beats) loaded as
// int4/float4 vectors per batch; normal (cached) streaming stores.
// out[b,f,:] = G[b,ind,:] + Q[f,:] + pitch*wp + EB[beat]
// ---------------------------------------------------------------------------
__global__ __launch_bounds__(256) void k_final(const float* __restrict__ G,
                                               const float* __restrict__ Q,
                                               const int* __restrict__ inds,
                                               const float* __restrict__ pitch,
                                               const int* __restrict__ beats,
                                               const float* __restrict__ wp,
                                               const float* __restrict__ eb,
                                               float* __restrict__ out) {
    // bijective XCD swizzle: 1024 blocks, 8 XCDs, 128 chunks each
    int swz = (blockIdx.x & 7) * 128 + (blockIdx.x >> 3);
    int f0 = swz * 8;
    int wv = threadIdx.x >> 6, lane = threadIdx.x & 63;
    f32x4 w4 = ((const f32x4*)wp)[lane];
    f32x4 e0 = ((const f32x4*)eb)[lane];
    f32x4 e1 = ((const f32x4*)eb)[64 + lane];
    f32x4 q[8];
#pragma unroll
    for (int f = 0; f < 8; ++f) q[f] = ((const f32x4*)Q)[(f0 + f) * 64 + lane];
#pragma unroll
    for (int bb = 0; bb < 4; ++bb) {
        int b = wv * 4 + bb;
        int idx0 = b * FRAMES + f0;
        int4 i0 = *(const int4*)(inds + idx0);
        int4 i1 = *(const int4*)(inds + idx0 + 4);
        f32x4 p0 = *(const f32x4*)(pitch + idx0);
        f32x4 p1 = *(const f32x4*)(pitch + idx0 + 4);
        int4 t0 = *(const int4*)(beats + idx0);
        int4 t1 = *(const int4*)(beats + idx0 + 4);
        int indv[8] = {i0.x, i0.y, i0.z, i0.w, i1.x, i1.y, i1.z, i1.w};
        float pv[8] = {p0[0], p0[1], p0[2], p0[3], p1[0], p1[1], p1[2], p1[3]};
        int btv[8] = {t0.x, t0.y, t0.z, t0.w, t1.x, t1.y, t1.z, t1.w};
#pragma unroll
        for (int f = 0; f < 8; ++f) {
            f32x4 g = ((const f32x4*)G)[(b * TLEN + indv[f]) * 64 + lane];
            f32x4 e = btv[f] ? e1 : e0;
            f32x4 r;
#pragma unroll
            for (int i = 0; i < 4; ++i) r[i] = g[i] + q[f][i] + pv[f] * w4[i] + e[i];
            ((f32x4*)out)[(idx0 + f) * 64 + lane] = r;
        }
    }
}

extern "C" void kernel_launch(void* const* d_in, const int* in_sizes, int n_in,
                              void* d_out, int out_size, void* d_ws, size_t ws_size,
                              hipStream_t stream) {
    const float* enc   = (const float*)d_in[0];  // [16,512,256]
    const int*   ap    = (const int*)d_in[1];    // [16,8192]
    const int*   tp    = (const int*)d_in[2];    // [16,512]
    const float* pitch = (const float*)d_in[3];  // [16,8192,1]
    const int*   beats = (const int*)d_in[4];    // [16,8192,1]
    const float* wpit  = (const float*)d_in[5];  // [256,1]
    const float* bpit  = (const float*)d_in[6];  // [256]
    const float* wpos  = (const float*)d_in[7];  // [256,256]
    const float* bpos  = (const float*)d_in[8];  // [256]
    const float* ebts  = (const float*)d_in[9];  // [2,256]
    float* out = (float*)d_out;
    char* ws = (char*)d_ws;
    int*   inds = (int*)ws;                   // 512 KB
    float* G    = (float*)(ws + (1 << 20));   // 8 MB
    float* Q    = (float*)(ws + (9 << 20));   // 8 MB

    hipLaunchKernelGGL(k_prep, dim3(256), dim3(512), 0, stream,
                       enc, wpos, bpos, bpit, ap, tp, G, Q, inds);
    hipLaunchKernelGGL(k_final, dim3(1024), dim3(256), 0, stream,
                       G, Q, inds, pitch, beats, wpit, ebts, out);
}

// Round 7
// 44.331 us; speedup vs baseline: 1.0388x; 1.0051x over previous
//
#include <hip/hip_runtime.h>
#include <hip/hip_bf16.h>

#define BATCH 16
#define FRAMES 8192
#define TLEN 512
#define EDIM 256
#define SP 56  // LDS row stride in shorts (112B): 16B-aligned, 2-way bank aliasing max

typedef __attribute__((ext_vector_type(8))) short short8;
typedef __attribute__((ext_vector_type(4))) float f32x4;

__device__ __forceinline__ unsigned cvt2(float lo, float hi) {
    __hip_bfloat162 t = __float22bfloat162_rn(make_float2(lo, hi));  // v_cvt_pk_bf16_f32
    return *reinterpret_cast<unsigned*>(&t);
}
__device__ __forceinline__ unsigned long long pack4(f32x4 u) {
    return (unsigned long long)cvt2(u[0], u[1]) |
           ((unsigned long long)cvt2(u[2], u[3]) << 32);
}

// ---------------------------------------------------------------------------
// k_prep (256 blocks, 512 thr)  [round-5/6 proven, unchanged]:
//   blocks 0..127   G[row][d] = sum_e enc[row][e]*(W+I)[d][e]  (= enc + enc·Wt)
//   blocks 128..255 Q[f][d]   = sum_e PE[f][e]*W[d][e] + pos_b[d]+pit_b[d]
//   blocks 240..255 ALSO run the aligner scan for batch (bid-240) BEFORE GEMM
// ---------------------------------------------------------------------------
__global__ __launch_bounds__(512) void k_prep(const float* __restrict__ X,
                                              const float* __restrict__ W,
                                              const float* __restrict__ pos_b,
                                              const float* __restrict__ pit_b,
                                              const int* __restrict__ ap,
                                              const int* __restrict__ tp,
                                              float* __restrict__ G,
                                              float* __restrict__ Q,
                                              int* __restrict__ inds) {
    __shared__ short lds[(64 + 256) * SP];  // 35840 B
    int bid = blockIdx.x;
    int tid = threadIdx.x;

    if (bid >= 240) {
        // ---------------- aligner scan (then fall through to GEMM) ----------
        int b = bid - 240;
        int* tps = (int*)lds;          // 512 ints
        int* wsum = tps + TLEN;        // 8 ints
        int* okp = wsum + 8;
        const int* apb = ap + b * FRAMES;
        tps[tid] = tp[b * TLEN + tid];
        if (tid == 0) *okp = 1;
        __syncthreads();
        int j0 = tid * 16;
        int4 v0 = ((const int4*)apb)[tid * 4];
        int4 v1 = ((const int4*)apb)[tid * 4 + 1];
        int4 v2 = ((const int4*)apb)[tid * 4 + 2];
        int4 v3 = ((const int4*)apb)[tid * 4 + 3];
        int a[16] = {v0.x, v0.y, v0.z, v0.w, v1.x, v1.y, v1.z, v1.w,
                     v2.x, v2.y, v2.z, v2.w, v3.x, v3.y, v3.z, v3.w};
        int pr = (tid == 0) ? a[0] : apb[j0 - 1];
        int c = 0, p[16];
#pragma unroll
        for (int k = 0; k < 16; ++k) {
            c += ((j0 + k) > 0) && (a[k] != pr);
            p[k] = c;
            pr = a[k];
        }
        int lane = tid & 63, wv = tid >> 6;
        int sc = c;
#pragma unroll
        for (int d = 1; d < 64; d <<= 1) {
            int o = __shfl_up(sc, d);
            if (lane >= d) sc += o;
        }
        if (lane == 63) wsum[wv] = sc;
        __syncthreads();
        int wbase = 0;
        for (int w = 0; w < wv; ++w) wbase += wsum[w];
        int excl = wbase + sc - c;
        int g[16];
#pragma unroll
        for (int k = 0; k < 16; ++k) g[k] = min(excl + p[k], TLEN - 1);
        int4* ob = (int4*)(inds + b * FRAMES);
#pragma unroll
        for (int q4 = 0; q4 < 4; ++q4) {
            int4 wv4;
            wv4.x = g[q4 * 4]; wv4.y = g[q4 * 4 + 1];
            wv4.z = g[q4 * 4 + 2]; wv4.w = g[q4 * 4 + 3];
            ob[tid * 4 + q4] = wv4;
        }
        int ok = 1, gp = min(excl, TLEN - 1);
#pragma unroll
        for (int k = 0; k < 16; ++k) {
            int j = j0 + k, e;
            if (j == 0) e = 0;
            else e = (a[k] == tps[gp]) ? gp : min(gp + 1, TLEN - 1);
            ok &= (g[k] == e);
            gp = g[k];
        }
        if (!ok) atomicAnd(okp, 0);
        __syncthreads();
        if (*okp == 0 && tid == 0) {  // exact serial fallback (never for this input)
            int ind = 0, cur = tps[0];
            int* o = inds + b * FRAMES;
            o[0] = 0;
            for (int j = 1; j < FRAMES; ++j) {
                int aj = apb[j];
                if (aj != cur && ind < TLEN - 1) { ind++; cur = tps[ind]; }
                o[j] = ind;
            }
        }
        // fall through to GEMM (first loop iteration starts with __syncthreads)
    }

    // ---------------- GEMM path ----------------
    int qmode = (bid >= 128);
    int row0 = (qmode ? bid - 128 : bid) * 64;
    short* Xs = lds;            // 64 x SP
    short* Ws = lds + 64 * SP;  // 256 x SP
    int lane = tid & 63, wv = tid >> 6;
    int c = lane & 15, gq = lane >> 4;
    int r0 = (wv & 3) * 16, cc0 = (wv >> 2) * 128;
    int sr = tid >> 3, spart = tid & 7;  // staging decomposition
    f32x4 acc[8];
#pragma unroll
    for (int i = 0; i < 8; ++i) acc[i] = (f32x4){0.f, 0.f, 0.f, 0.f};

    const float kPE = -0.03597789207803197f;     // -ln(10000)/256
    const float INV2PI = 0.15915494309189535f;

    for (int ks = 0; ks < 8; ++ks) {
        int k0 = ks * 32;
        __syncthreads();
        {   // stage X tile [64 r][32 k] (4 elems/thread)
            unsigned long long pk;
            if (!qmode) {
                f32x4 u = *(const f32x4*)(X + (row0 + sr) * EDIM + k0 + spart * 4);
                pk = pack4(u);
            } else {
                float fr = (float)(row0 + sr);
                int e0 = k0 + spart * 4;
                float dv0 = __expf((float)e0 * kPE);
                float dv1 = __expf((float)(e0 + 2) * kPE);
                float a0 = fr * dv0 * INV2PI; a0 -= floorf(a0);
                float a1 = fr * dv1 * INV2PI; a1 -= floorf(a1);
                f32x4 v;
                v[0] = __builtin_amdgcn_sinf(a0);
                v[1] = __builtin_amdgcn_cosf(a0);
                v[2] = __builtin_amdgcn_sinf(a1);
                v[3] = __builtin_amdgcn_cosf(a1);
                pk = pack4(v);
            }
            *((unsigned long long*)&Xs[sr * SP + spart * 4]) = pk;
        }
#pragma unroll
        for (int m = 0; m < 4; ++m) {  // stage W tile [256 d][32 k], +I for G-path
            int d = sr + 64 * m;
            f32x4 u = *(const f32x4*)(W + d * EDIM + k0 + spart * 4);
            if (!qmode) {
#pragma unroll
                for (int j = 0; j < 4; ++j)
                    if (d == k0 + spart * 4 + j) u[j] += 1.0f;
            }
            *((unsigned long long*)&Ws[d * SP + spart * 4]) = pack4(u);
        }
        __syncthreads();
        short8 af = *((const short8*)&Xs[(r0 + c) * SP + gq * 8]);
#pragma unroll
        for (int tc = 0; tc < 8; ++tc) {
            short8 bf = *((const short8*)&Ws[(cc0 + tc * 16 + c) * SP + gq * 8]);
            acc[tc] = __builtin_amdgcn_mfma_f32_16x16x32_bf16(af, bf, acc[tc], 0, 0, 0);
        }
    }
    // epilogue: C/D layout col=lane&15, row=(lane>>4)*4+i
    int mrow = row0 + r0 + gq * 4;
    if (!qmode) {
#pragma unroll
        for (int tc = 0; tc < 8; ++tc) {
            int d = cc0 + tc * 16 + c;
#pragma unroll
            for (int i = 0; i < 4; ++i)
                G[(mrow + i) * EDIM + d] = acc[tc][i];
        }
    } else {
#pragma unroll
        for (int tc = 0; tc < 8; ++tc) {
            int d = cc0 + tc * 16 + c;
            float bb = pos_b[d] + pit_b[d];
#pragma unroll
            for (int i = 0; i < 4; ++i)
                Q[(mrow + i) * EDIM + d] = acc[tc][i] + bb;
        }
    }
}

// ---------------------------------------------------------------------------
// k_final v4: 2048 blocks x 256 thr; block owns 4 frames x 16 batches; wave
// owns 4 frames x 4 batches (batch groups of 4 -> ~16 independent gathers in
// flight, bounded VGPR). XCD-chunked bijective swizzle (2048 = 8 x 256).
// out[b,f,:] = G[b,ind,:] + Q[f,:] + pitch*wp + EB[beat]
// ---------------------------------------------------------------------------
__global__ __launch_bounds__(256) void k_final(const float* __restrict__ G,
                                               const float* __restrict__ Q,
                                               const int* __restrict__ inds,
                                               const float* __restrict__ pitch,
                                               const int* __restrict__ beats,
                                               const float* __restrict__ wp,
                                               const float* __restrict__ eb,
                                               float* __restrict__ out) {
    int swz = (blockIdx.x & 7) * 256 + (blockIdx.x >> 3);
    int f0 = swz * 4;
    int wv = threadIdx.x >> 6, lane = threadIdx.x & 63;
    f32x4 w4 = ((const f32x4*)wp)[lane];
    f32x4 e0 = ((const f32x4*)eb)[lane];
    f32x4 e1 = ((const f32x4*)eb)[64 + lane];
    f32x4 q[4];
#pragma unroll
    for (int f = 0; f < 4; ++f) q[f] = ((const f32x4*)Q)[(f0 + f) * 64 + lane];
#pragma unroll
    for (int bg = 0; bg < 1; ++bg) {  // batch groups handled below (wave owns 4)
        ;
    }
#pragma unroll
    for (int bb = 0; bb < 4; ++bb) {
        int b = wv * 4 + bb;
        int idx0 = b * FRAMES + f0;
        int4 iv = *(const int4*)(inds + idx0);
        f32x4 pv4 = *(const f32x4*)(pitch + idx0);
        int4 tv = *(const int4*)(beats + idx0);
        int indv[4] = {iv.x, iv.y, iv.z, iv.w};
        float pv[4] = {pv4[0], pv4[1], pv4[2], pv4[3]};
        int btv[4] = {tv.x, tv.y, tv.z, tv.w};
#pragma unroll
        for (int f = 0; f < 4; ++f) {
            f32x4 g = ((const f32x4*)G)[(b * TLEN + indv[f]) * 64 + lane];
            f32x4 e = btv[f] ? e1 : e0;
            f32x4 r;
#pragma unroll
            for (int i = 0; i < 4; ++i) r[i] = g[i] + q[f][i] + pv[f] * w4[i] + e[i];
            ((f32x4*)out)[(idx0 + f) * 64 + lane] = r;
        }
        // remaining 12 batches: strided by 4 waves' partitioning below
    }
    // waves cover batches {wv*4..wv*4+3}; 4 waves x 4 = 16 batches: done above.
}

extern "C" void kernel_launch(void* const* d_in, const int* in_sizes, int n_in,
                              void* d_out, int out_size, void* d_ws, size_t ws_size,
                              hipStream_t stream) {
    const float* enc   = (const float*)d_in[0];  // [16,512,256]
    const int*   ap    = (const int*)d_in[1];    // [16,8192]
    const int*   tp    = (const int*)d_in[2];    // [16,512]
    const float* pitch = (const float*)d_in[3];  // [16,8192,1]
    const int*   beats = (const int*)d_in[4];    // [16,8192,1]
    const float* wpit  = (const float*)d_in[5];  // [256,1]
    const float* bpit  = (const float*)d_in[6];  // [256]
    const float* wpos  = (const float*)d_in[7];  // [256,256]
    const float* bpos  = (const float*)d_in[8];  // [256]
    const float* ebts  = (const float*)d_in[9];  // [2,256]
    float* out = (float*)d_out;
    char* ws = (char*)d_ws;
    int*   inds = (int*)ws;                   // 512 KB
    float* G    = (float*)(ws + (1 << 20));   // 8 MB
    float* Q    = (float*)(ws + (9 << 20));   // 8 MB

    hipLaunchKernelGGL(k_prep, dim3(256), dim3(512), 0, stream,
                       enc, wpos, bpos, bpit, ap, tp, G, Q, inds);
    hipLaunchKernelGGL(k_final, dim3(2048), dim3(256), 0, stream,
                       G, Q, inds, pitch, beats, wpit, ebts, out);
}